// Round 5
// baseline (143.822 us; speedup 1.0000x reference)
//
#include <hip/hip_runtime.h>
#include <hip/hip_bf16.h>
#include <stdint.h>

#define H_NUM 16
#define DH 64
#define TSEQ 2048
#define CDIM 1024

typedef short shortx8 __attribute__((ext_vector_type(8)));
typedef float f32x4 __attribute__((ext_vector_type(4)));
typedef unsigned short u16;
typedef unsigned int u32;
typedef unsigned long long u64;

#define MFMA16(a,b,c) __builtin_amdgcn_mfma_f32_16x16x32_bf16(a,b,c,0,0,0)

static __device__ __forceinline__ u16 f2bf(float f) {
  union { float f; u32 u; } v; v.f = f;
  u32 r = v.u + 0x7fffu + ((v.u >> 16) & 1u);
  return (u16)(r >> 16);
}
static __device__ __forceinline__ float bf2f(u16 b) {
  union { u32 u; float f; } v; v.u = ((u32)b) << 16;
  return v.f;
}

static __device__ __forceinline__ void gload_lds16(const void* g, void* l) {
  __builtin_amdgcn_global_load_lds(
    (const __attribute__((address_space(1))) void*)g,
    (__attribute__((address_space(3))) void*)l, 16, 0, 0);
}

// ---------------- fused prep: cast x -> bf16, transpose W_attn & W_proj -> bf16 ----------------
extern "C" __global__ __launch_bounds__(1024) void k_prep(
    const float* __restrict__ x, u16* __restrict__ xb,
    const float* __restrict__ Wa, u16* __restrict__ wat,
    const float* __restrict__ Wp, u16* __restrict__ wpt)
{
  __shared__ float t[32][33];
  int bid = blockIdx.x, tid = threadIdx.x;
  if (bid < 1024) {
    int i = bid * 1024 + tid;
    float4 v = ((const float4*)x)[i];
    union { u16 h[4]; uint2 u; } o;
    o.h[0] = f2bf(v.x); o.h[1] = f2bf(v.y); o.h[2] = f2bf(v.z); o.h[3] = f2bf(v.w);
    ((uint2*)xb)[i] = o.u;
    return;
  }
  const float* in; u16* out; int Ccols, bx, by;
  if (bid < 4096) { int tt = bid - 1024; in = Wa; out = wat; Ccols = 3072; bx = tt % 96; by = tt / 96; }
  else            { int tt = bid - 4096; in = Wp; out = wpt; Ccols = 1024; bx = tt & 31; by = tt >> 5; }
  int tx = tid & 31, ty = tid >> 5;
  int c0 = bx * 32, r0 = by * 32;
  t[ty][tx] = in[(size_t)(r0 + ty) * Ccols + c0 + tx];
  __syncthreads();
  out[(size_t)(c0 + ty) * 1024 + r0 + tx] = f2bf(t[tx][ty]);
}

// ---------------- 8-phase 256x256 GEMM (BK=64, k-split LDS units): C = A * Bt^T + bias ----------------
// 512 threads = 8 waves (wm = w>>2 in 0..1, wn = w&3 in 0..3); per-wave C: 128x64.
// LDS [buf][khalf][256 rows][32 k] bf16, 16KB units; unit = 2 gload_lds (512 thr x 16B),
// linear dest, source chunk pre-swizzled (c ^ (row>>1)&3) so fragment ds_reads are 2-way max.
// Phase a (0..7): compute tile T+(a>>2) [buf a>>2], khalf (a>>1)&1, m-half a&1 (16 MFMA);
// stage order: a0 A-k1(T+1), a1 B-k1(T+1), a2 A-k0(T+2), a3 B-k0(T+2), a4 A-k1(T+2),
// a5 B-k1(T+2), a6 A-k0(T+3), a7 B-k0(T+3). Every unit staged >=4 phases before first read;
// counted s_waitcnt vmcnt(8) at odd a (before mid-barrier) covers the next k-step's units
// (verified by enumeration incl. prologue and clamped tail: out-of-range stages clamp the
// SOURCE tile so issue cadence and vmcnt arithmetic stay uniform; clamped data never read).
// Write-after-read: a phase's stage region was last ds_read >=1 end-barrier earlier.
extern "C" __global__ __launch_bounds__(512) void k_gemm_8p(
    const u16* __restrict__ A, const u16* __restrict__ Bt,
    const float* __restrict__ bias, u16* __restrict__ Cout,
    int M, int N, int K)
{
  __shared__ u16 ldsA[2][2][256 * 32];
  __shared__ u16 ldsB[2][2][256 * 32];
  int tid = threadIdx.x;
  int w = tid >> 6, l = tid & 63;
  int lg = l >> 4, lr = l & 15;
  int wm = w >> 2, wn = w & 3;
  int nwg = gridDim.x * gridDim.y;
  int lin = blockIdx.y * gridDim.x + blockIdx.x;
  int cpx = nwg >> 3;
  int swz = (lin & 7) * cpx + (lin >> 3);
  int m0 = (swz / gridDim.x) * 256, n0 = (swz % gridDim.x) * 256;

  f32x4 acc[8][4];
#pragma unroll
  for (int i = 0; i < 8; ++i)
#pragma unroll
    for (int j = 0; j < 4; ++j) acc[i][j] = (f32x4){0.f, 0.f, 0.f, 0.f};

  auto STAGE_U = [&](const u16* base, int x0, int t, int kh, u16* region) {
#pragma unroll
    for (int j = 0; j < 2; ++j) {
      int row = j * 128 + (tid >> 2);
      int c = (tid & 3) ^ ((row >> 1) & 3);
      gload_lds16(base + (size_t)(x0 + row) * K + t * 64 + kh * 32 + c * 8,
                  (char*)region + j * 8192 + w * 1024);
    }
  };

  int NT = K >> 6;
  // prologue: tile0 k0,k1 and tile1 k0 (12 loads/wave); vmcnt(8) -> tile0.k0 landed
  STAGE_U(A,  m0, 0, 0, ldsA[0][0]);
  STAGE_U(Bt, n0, 0, 0, ldsB[0][0]);
  STAGE_U(A,  m0, 0, 1, ldsA[0][1]);
  STAGE_U(Bt, n0, 0, 1, ldsB[0][1]);
  STAGE_U(A,  m0, 1, 0, ldsA[1][0]);
  STAGE_U(Bt, n0, 1, 0, ldsB[1][0]);
  asm volatile("s_waitcnt vmcnt(8)" ::: "memory");
  __syncthreads();

  for (int T = 0; T < NT; T += 2) {
    int t2 = (T + 2 < NT) ? T + 2 : NT - 1;
    int t3 = (T + 3 < NT) ? T + 3 : NT - 1;
#pragma unroll
    for (int a = 0; a < 8; ++a) {
      int cbuf = a >> 2;          // buffer of computed tile (T even)
      int kh = (a >> 1) & 1;
      int mh = a & 1;
      // ds_read this phase's fragments (data vmcnt-ensured at an earlier phase barrier)
      shortx8 af[4], bfr[4];
#pragma unroll
      for (int mi = 0; mi < 4; ++mi) {
        int r = wm * 128 + (mh * 4 + mi) * 16 + lr;
        int c = lg ^ ((r >> 1) & 3);
        af[mi] = *(const shortx8*)((const char*)ldsA[cbuf][kh] + r * 64 + c * 16);
      }
#pragma unroll
      for (int ni = 0; ni < 4; ++ni) {
        int r = wn * 64 + ni * 16 + lr;
        int c = lg ^ ((r >> 1) & 3);
        bfr[ni] = *(const shortx8*)((const char*)ldsB[cbuf][kh] + r * 64 + c * 16);
      }
      // stage one 16KB unit (region freed by schedule; source tile clamped at tail)
      if      (a == 0) STAGE_U(A,  m0, T + 1, 1, ldsA[1][1]);
      else if (a == 1) STAGE_U(Bt, n0, T + 1, 1, ldsB[1][1]);
      else if (a == 2) STAGE_U(A,  m0, t2, 0, ldsA[0][0]);
      else if (a == 3) STAGE_U(Bt, n0, t2, 0, ldsB[0][0]);
      else if (a == 4) STAGE_U(A,  m0, t2, 1, ldsA[0][1]);
      else if (a == 5) STAGE_U(Bt, n0, t2, 1, ldsB[0][1]);
      else if (a == 6) STAGE_U(A,  m0, t3, 0, ldsA[1][0]);
      else             STAGE_U(Bt, n0, t3, 0, ldsB[1][0]);
      if (a & 1) asm volatile("s_waitcnt vmcnt(8)" ::: "memory");
      __syncthreads();
      __builtin_amdgcn_s_setprio(1);
#pragma unroll
      for (int mi = 0; mi < 4; ++mi)
#pragma unroll
        for (int ni = 0; ni < 4; ++ni)
          acc[mh * 4 + mi][ni] = MFMA16(af[mi], bfr[ni], acc[mh * 4 + mi][ni]);
      __builtin_amdgcn_s_setprio(0);
      __syncthreads();
    }
  }
  // epilogue
#pragma unroll
  for (int mi = 0; mi < 8; ++mi)
#pragma unroll
    for (int ni = 0; ni < 4; ++ni) {
      int col = n0 + wn * 64 + ni * 16 + lr;
      float bz = bias[col];
#pragma unroll
      for (int rr = 0; rr < 4; ++rr) {
        int row = m0 + wm * 128 + mi * 16 + 4 * lg + rr;
        Cout[(size_t)row * N + col] = f2bf(acc[mi][ni][rr] + bz);
      }
    }
}

// ---------------- 2-phase pipelined GEMM: C[M][N] = A[M][K] * Bt[N][K]^T + bias ----------------
template<int OUT_BF16>
__global__ __launch_bounds__(256) void k_gemm_bt(
    const u16* __restrict__ A, const u16* __restrict__ Bt,
    const float* __restrict__ bias, void* __restrict__ Cout,
    int M, int N, int K)
{
  __shared__ u16 lds_a[2][128 * 32];
  __shared__ u16 lds_b[2][128 * 32];
  int tid = threadIdx.x;
  int w = tid >> 6, l = tid & 63;
  int lg = l >> 4, lr = l & 15;
  // bijective XCD swizzle (nwg % 8 == 0 for all our launches)
  int nwg = gridDim.x * gridDim.y;
  int lin = blockIdx.y * gridDim.x + blockIdx.x;
  int cpx = nwg >> 3;
  int swz = (lin & 7) * cpx + (lin >> 3);
  int m0 = (swz / gridDim.x) * 128, n0 = (swz % gridDim.x) * 128;
  int wm = w >> 1, wn = w & 1;
  f32x4 acc[4][4];
#pragma unroll
  for (int i = 0; i < 4; ++i)
#pragma unroll
    for (int j = 0; j < 4; ++j) acc[i][j] = (f32x4){0.f, 0.f, 0.f, 0.f};

  auto STAGE = [&](int k0, int buf) {
#pragma unroll
    for (int j = 0; j < 2; ++j) {
      int ci = w * 2 + j;
      gload_lds16(A  + (size_t)(m0 + ci * 16 + (l >> 2)) * K + k0 + (l & 3) * 8,
                  (char*)lds_a[buf] + ci * 1024);
      gload_lds16(Bt + (size_t)(n0 + ci * 16 + (l >> 2)) * K + k0 + (l & 3) * 8,
                  (char*)lds_b[buf] + ci * 1024);
    }
  };

  int nt = K >> 5;
  STAGE(0, 0);
  int cur = 0;
  for (int t = 0; t < nt; ++t) {
    asm volatile("s_waitcnt vmcnt(0)" ::: "memory");
    __syncthreads();
    if (t + 1 < nt) STAGE((t + 1) << 5, cur ^ 1);
    shortx8 af[4], bf[4];
#pragma unroll
    for (int i = 0; i < 4; ++i) {
      af[i] = *(const shortx8*)((const char*)lds_a[cur] + (64 * wm + 16 * i + lr) * 64 + lg * 16);
      bf[i] = *(const shortx8*)((const char*)lds_b[cur] + (64 * wn + 16 * i + lr) * 64 + lg * 16);
    }
    __builtin_amdgcn_s_setprio(1);
#pragma unroll
    for (int mi = 0; mi < 4; ++mi)
#pragma unroll
      for (int ni = 0; ni < 4; ++ni)
        acc[mi][ni] = MFMA16(af[mi], bf[ni], acc[mi][ni]);
    __builtin_amdgcn_s_setprio(0);
    cur ^= 1;
  }
  // epilogue
#pragma unroll
  for (int mi = 0; mi < 4; ++mi)
#pragma unroll
    for (int ni = 0; ni < 4; ++ni) {
      int col = n0 + 64 * wn + 16 * ni + lr;
      float bz = bias[col];
#pragma unroll
      for (int r = 0; r < 4; ++r) {
        int row = m0 + 64 * wm + 16 * mi + 4 * lg + r;
        float v = acc[mi][ni][r] + bz;
        if (OUT_BF16) ((u16*)Cout)[(size_t)row * N + col] = f2bf(v);
        else          ((float*)Cout)[(size_t)row * N + col] = v;
      }
    }
}

// ---------------- V transpose: qkv bf16 -> vt[bh*64+d][T] ----------------
extern "C" __global__ __launch_bounds__(256) void k_transpose_v(
    const u16* __restrict__ qkv, u16* __restrict__ vt)
{
  __shared__ u16 tile[64][72];
  int bh = blockIdx.y; int b = bh >> 4, h = bh & 15;
  int t0 = blockIdx.x * 64;
  int tid = threadIdx.x;
#pragma unroll
  for (int p = 0; p < 2; ++p) {
    int tr = p * 32 + (tid >> 3), dc = (tid & 7) * 8;
    shortx8 v = *(const shortx8*)(qkv + (size_t)(b * TSEQ + t0 + tr) * 3072 + 2 * CDIM + h * DH + dc);
    *(shortx8*)&tile[tr][dc] = v;
  }
  __syncthreads();
#pragma unroll
  for (int p = 0; p < 2; ++p) {
    int dr = p * 32 + (tid >> 3), tc = (tid & 7) * 8;
    shortx8 o;
#pragma unroll
    for (int j = 0; j < 8; ++j) o[j] = (short)tile[tc + j][dr];
    *(shortx8*)(vt + (size_t)(bh * DH + dr) * TSEQ + t0 + tc) = o;
  }
}

// ---------------- flash attention, causal, paired q-tiles, software-pipelined ----------------
// (byte-identical to the round-4 green kernel)
extern "C" __global__ __launch_bounds__(256) void k_attn(
    const u16* __restrict__ qkv, const u16* __restrict__ vt, u16* __restrict__ yb)
{
  __shared__ u16 lds_k[3][64 * 64];   // [buf][kv][d], XOR-swizzled chunks
  __shared__ u16 lds_v[3][64 * 64];   // [buf][d][kv], XOR-swizzled chunks
  __shared__ u16 lds_p[4 * 1024];     // per-wave [16 q][64 kv]
  // XCD-aware decode: xcd = d&7 fixed per (b,h) panel group
  int d = blockIdx.x;                 // 0..511
  int xcd = d & 7, j = d >> 3;        // j 0..63
  int hb = xcd + 8 * (j >> 4);        // 0..31, 4 panels per XCD
  int bx = j & 15;                    // q-pair 0..15
  int h = hb & 15, b = hb >> 4;
  int tid = threadIdx.x, w = tid >> 6, l = tid & 63;
  int lg = l >> 4, lr = l & 15;
  const float QSCALE = 0.18033688011112042f;  // 0.125 * log2(e)
  const u16* vbase = vt + (size_t)(b * H_NUM + h) * DH * TSEQ;
  u16* pw = lds_p + w * 1024;

  auto STAGE = [&](int kv0, int buf) {
#pragma unroll
    for (int jj = 0; jj < 2; ++jj) {
      int ci = w * 2 + jj;
      int row = ci * 8 + (l >> 3);
      int a = ((l & 7) ^ (row & 7)) * 8;
      gload_lds16(qkv + (size_t)(b * TSEQ + kv0 + row) * 3072 + CDIM + h * DH + a,
                  (char*)lds_k[buf] + ci * 1024);
      gload_lds16(vbase + (size_t)row * TSEQ + kv0 + a,
                  (char*)lds_v[buf] + ci * 1024);
    }
  };

  for (int qi = 0; qi < 2; ++qi) {
    int qb = qi ? (31 - bx) : bx;
    int q0 = qb * 64;

    // Q fragments, pre-scaled by 0.125*log2e
    int qrow = q0 + 16 * w + lr;
    const u16* qp = qkv + (size_t)(b * TSEQ + qrow) * 3072 + h * DH;
    shortx8 qf[2];
#pragma unroll
    for (int s_ = 0; s_ < 2; ++s_) {
      shortx8 v = *(const shortx8*)(qp + s_ * 32 + lg * 8);
#pragma unroll
      for (int i = 0; i < 8; ++i) v[i] = (short)f2bf(bf2f((u16)v[i]) * QSCALE);
      qf[s_] = v;
    }

    f32x4 yacc[4];
#pragma unroll
    for (int i = 0; i < 4; ++i) yacc[i] = (f32x4){0.f, 0.f, 0.f, 0.f};
    float m_run[4] = {-3.0e38f, -3.0e38f, -3.0e38f, -3.0e38f};
    float l_part[4] = {0.f, 0.f, 0.f, 0.f};
    f32x4 s[4];

    auto QKT = [&](int buf) {
#pragma unroll
      for (int idx = 0; idx < 4; ++idx) s[idx] = (f32x4){0.f, 0.f, 0.f, 0.f};
      int kswz = (lr & 7) << 4;
#pragma unroll
      for (int idx = 0; idx < 4; ++idx) {
        const char* kb_ = (const char*)lds_k[buf] + (idx * 16 + lr) * 128;
#pragma unroll
        for (int d0 = 0; d0 < 2; ++d0) {
          shortx8 kf = *(const shortx8*)(kb_ + ((d0 * 64 + lg * 16) ^ kswz));
          s[idx] = MFMA16(qf[d0], kf, s[idx]);
        }
      }
    };

    auto SOFTMAX = [&](int kv0) {
      if (kv0 == q0) {  // diagonal tile: apply causal mask
#pragma unroll
        for (int idx = 0; idx < 4; ++idx)
#pragma unroll
          for (int r = 0; r < 4; ++r) {
            int row_l = 16 * w + 4 * lg + r;
            if (idx * 16 + lr > row_l) s[idx][r] = -3.0e38f;
          }
      }
#pragma unroll
      for (int r = 0; r < 4; ++r) {
        float a0 = s[0][r], a1 = s[1][r], a2 = s[2][r], a3 = s[3][r];
        float pmax = fmaxf(fmaxf(a0, a1), fmaxf(a2, a3));
        float mr = m_run[r];
        u64 bal = __ballot(pmax > mr + 8.0f);
        if ((bal >> (lg * 16)) & 0xFFFFull) {
          float gm = pmax;
          gm = fmaxf(gm, __shfl_xor(gm, 1));
          gm = fmaxf(gm, __shfl_xor(gm, 2));
          gm = fmaxf(gm, __shfl_xor(gm, 4));
          gm = fmaxf(gm, __shfl_xor(gm, 8));
          float mn = fmaxf(mr, gm);
          float al = __builtin_amdgcn_exp2f(mr - mn);
          l_part[r] *= al;
#pragma unroll
          for (int dt = 0; dt < 4; ++dt) yacc[dt][r] *= al;
          m_run[r] = mn; mr = mn;
        }
        float p0 = __builtin_amdgcn_exp2f(a0 - mr);
        float p1 = __builtin_amdgcn_exp2f(a1 - mr);
        float p2 = __builtin_amdgcn_exp2f(a2 - mr);
        float p3 = __builtin_amdgcn_exp2f(a3 - mr);
        l_part[r] += (p0 + p1) + (p2 + p3);
        u32 pk01, pk23;
        asm("v_cvt_pk_bf16_f32 %0, %1, %2" : "=v"(pk01) : "v"(p0), "v"(p1));
        asm("v_cvt_pk_bf16_f32 %0, %1, %2" : "=v"(pk23) : "v"(p2), "v"(p3));
        int q = 4 * lg + r;
        int rb = q * 64, swq = (q & 7) << 3;
        pw[rb + ((lr)      ^ swq)] = (u16)pk01;
        pw[rb + ((16 + lr) ^ swq)] = (u16)(pk01 >> 16);
        pw[rb + ((32 + lr) ^ swq)] = (u16)pk23;
        pw[rb + ((48 + lr) ^ swq)] = (u16)(pk23 >> 16);
      }
    };

    auto PV = [&](int buf) {
      int pswz = (lr & 7) << 4;
#pragma unroll
      for (int c = 0; c < 2; ++c) {
        shortx8 pa = *(const shortx8*)((const char*)pw + lr * 128 + ((c * 64 + lg * 16) ^ pswz));
#pragma unroll
        for (int dt = 0; dt < 4; ++dt) {
          int vr = dt * 16 + lr;
          shortx8 vf = *(const shortx8*)((const char*)lds_v[buf] + vr * 128 +
                         ((c * 64 + lg * 16) ^ ((vr & 7) << 4)));
          yacc[dt] = MFMA16(pa, vf, yacc[dt]);
        }
      }
    };

    int nt = qb + 1;
    __syncthreads();            // all waves done reading LDS from previous qi
    STAGE(0, 0);
    asm volatile("s_waitcnt vmcnt(0)" ::: "memory");
    __syncthreads();            // buf0 complete & visible
    __builtin_amdgcn_s_setprio(1);
    QKT(0);
    __builtin_amdgcn_s_setprio(0);
    if (nt > 1) STAGE(64, 1);
    SOFTMAX(0);

    int vb = 0;                 // phase t: V from vb = t%3, K from kb = (t+1)%3
    for (int t = 0; t < nt; ++t) {
      int kb = vb + 1; if (kb == 3) kb = 0;
      int st = kb + 1; if (st == 3) st = 0;
      asm volatile("s_waitcnt vmcnt(0)" ::: "memory");
      __syncthreads();          // staged data (incl. buf kb) complete & visible
      __builtin_amdgcn_s_setprio(1);
      if (t + 1 < nt) QKT(kb);  // 8 MFMA, next tile's scores
      PV(vb);                   // 8 MFMA, this tile's PV (P written last phase)
      __builtin_amdgcn_s_setprio(0);
      if (t + 2 < nt) STAGE((t + 2) * 64, st);
      if (t + 1 < nt) SOFTMAX((t + 1) * 64);  // overlaps other wave's MFMA cluster
      vb = kb;
    }

    // epilogue: reduce deferred l, normalize, store
#pragma unroll
    for (int r = 0; r < 4; ++r) {
      float lsum = l_part[r];
      lsum += __shfl_xor(lsum, 1);
      lsum += __shfl_xor(lsum, 2);
      lsum += __shfl_xor(lsum, 4);
      lsum += __shfl_xor(lsum, 8);
      float inv = 1.0f / lsum;
      int row = q0 + 16 * w + 4 * lg + r;
      u16* yp = yb + (size_t)(b * TSEQ + row) * CDIM + h * DH;
#pragma unroll
      for (int dt = 0; dt < 4; ++dt)
        yp[dt * 16 + lr] = f2bf(yacc[dt][r] * inv);
    }
  }
}

extern "C" void kernel_launch(void* const* d_in, const int* in_sizes, int n_in,
                              void* d_out, int out_size, void* d_ws, size_t ws_size,
                              hipStream_t stream) {
  const float* x      = (const float*)d_in[0];
  const float* W_attn = (const float*)d_in[2];
  const float* b_attn = (const float*)d_in[3];
  const float* W_proj = (const float*)d_in[4];
  const float* b_proj = (const float*)d_in[5];

  char* ws = (char*)d_ws;
  u16* xb  = (u16*)ws;                         // 8 MB  [4096][1024]
  u16* wat = (u16*)(ws + (8ull  << 20));       // 6 MB  [3072][1024]
  u16* wpt = (u16*)(ws + (14ull << 20));       // 2 MB  [1024][1024]
  u16* qkv = (u16*)(ws + (16ull << 20));       // 24 MB [4096][3072]
  u16* vt  = (u16*)(ws + (40ull << 20));       // 8 MB  [32*64][2048]
  u16* yb  = (u16*)(ws + (48ull << 20));       // 8 MB  [4096][1024]

  k_prep<<<dim3(5120), dim3(1024), 0, stream>>>(x, xb, W_attn, wat, W_proj, wpt);
  k_gemm_8p<<<dim3(12, 16), dim3(512), 0, stream>>>(xb, wat, b_attn, qkv, 4096, 3072, 1024);
  k_transpose_v<<<dim3(32, 32), dim3(256), 0, stream>>>(qkv, vt);
  k_attn<<<dim3(512), dim3(256), 0, stream>>>(qkv, vt, yb);
  k_gemm_bt<0><<<dim3(8, 32), dim3(256), 0, stream>>>(yb, wpt, b_proj, d_out, 4096, 1024, 1024);
}

// Round 6
// 123.206 us; speedup vs baseline: 1.1673x; 1.1673x over previous
//
#include <hip/hip_runtime.h>
#include <hip/hip_bf16.h>
#include <stdint.h>

#define H_NUM 16
#define DH 64
#define TSEQ 2048
#define CDIM 1024

typedef short shortx8 __attribute__((ext_vector_type(8)));
typedef short shortx4 __attribute__((ext_vector_type(4)));
typedef float f32x4 __attribute__((ext_vector_type(4)));
typedef unsigned short u16;
typedef unsigned int u32;
typedef unsigned long long u64;

#define MFMA16(a,b,c) __builtin_amdgcn_mfma_f32_16x16x32_bf16(a,b,c,0,0,0)

static __device__ __forceinline__ u16 f2bf(float f) {
  union { float f; u32 u; } v; v.f = f;
  u32 r = v.u + 0x7fffu + ((v.u >> 16) & 1u);
  return (u16)(r >> 16);
}
static __device__ __forceinline__ float bf2f(u16 b) {
  union { u32 u; float f; } v; v.u = ((u32)b) << 16;
  return v.f;
}

static __device__ __forceinline__ void gload_lds16(const void* g, void* l) {
  __builtin_amdgcn_global_load_lds(
    (const __attribute__((address_space(1))) void*)g,
    (__attribute__((address_space(3))) void*)l, 16, 0, 0);
}

// ---------------- fused prep: cast x -> bf16, transpose W_attn & W_proj -> bf16 ----------------
extern "C" __global__ __launch_bounds__(1024) void k_prep(
    const float* __restrict__ x, u16* __restrict__ xb,
    const float* __restrict__ Wa, u16* __restrict__ wat,
    const float* __restrict__ Wp, u16* __restrict__ wpt)
{
  __shared__ float t[32][33];
  int bid = blockIdx.x, tid = threadIdx.x;
  if (bid < 1024) {
    int i = bid * 1024 + tid;
    float4 v = ((const float4*)x)[i];
    union { u16 h[4]; uint2 u; } o;
    o.h[0] = f2bf(v.x); o.h[1] = f2bf(v.y); o.h[2] = f2bf(v.z); o.h[3] = f2bf(v.w);
    ((uint2*)xb)[i] = o.u;
    return;
  }
  const float* in; u16* out; int Ccols, bx, by;
  if (bid < 4096) { int tt = bid - 1024; in = Wa; out = wat; Ccols = 3072; bx = tt % 96; by = tt / 96; }
  else            { int tt = bid - 4096; in = Wp; out = wpt; Ccols = 1024; bx = tt & 31; by = tt >> 5; }
  int tx = tid & 31, ty = tid >> 5;
  int c0 = bx * 32, r0 = by * 32;
  t[ty][tx] = in[(size_t)(r0 + ty) * Ccols + c0 + tx];
  __syncthreads();
  out[(size_t)(c0 + ty) * 1024 + r0 + tx] = f2bf(t[tx][ty]);
}

// ---------------- QKV GEMM, 2-phase pipelined, fused V-transpose epilogue ----------------
// C[4096][3072] = A[4096][1024] * Wt[3072][1024]^T + bias. Proven 2-phase loop body.
// Epilogue: cols < 2048 (Q,K) -> qkv bf16 as before; cols >= 2048 (V) -> written
// TRANSPOSED into vt[((b*16+h)*64+dd)*2048 + t] (bit-identical values to the old
// separate k_transpose_v pass, which this replaces). The col<2048 branch is
// wave-uniform per (wn,ni) because the 2048 boundary is a multiple of 128.
extern "C" __global__ __launch_bounds__(256) void k_gemm_qkv(
    const u16* __restrict__ A, const u16* __restrict__ Bt,
    const float* __restrict__ bias, u16* __restrict__ qkv, u16* __restrict__ vt)
{
  const int K = 1024, N = 3072;
  __shared__ u16 lds_a[2][128 * 32];
  __shared__ u16 lds_b[2][128 * 32];
  int tid = threadIdx.x;
  int w = tid >> 6, l = tid & 63;
  int lg = l >> 4, lr = l & 15;
  int nwg = gridDim.x * gridDim.y;
  int lin = blockIdx.y * gridDim.x + blockIdx.x;
  int cpx = nwg >> 3;
  int swz = (lin & 7) * cpx + (lin >> 3);
  int m0 = (swz / gridDim.x) * 128, n0 = (swz % gridDim.x) * 128;
  int wm = w >> 1, wn = w & 1;
  f32x4 acc[4][4];
#pragma unroll
  for (int i = 0; i < 4; ++i)
#pragma unroll
    for (int j = 0; j < 4; ++j) acc[i][j] = (f32x4){0.f, 0.f, 0.f, 0.f};

  auto STAGE = [&](int k0, int buf) {
#pragma unroll
    for (int j = 0; j < 2; ++j) {
      int ci = w * 2 + j;
      gload_lds16(A  + (size_t)(m0 + ci * 16 + (l >> 2)) * K + k0 + (l & 3) * 8,
                  (char*)lds_a[buf] + ci * 1024);
      gload_lds16(Bt + (size_t)(n0 + ci * 16 + (l >> 2)) * K + k0 + (l & 3) * 8,
                  (char*)lds_b[buf] + ci * 1024);
    }
  };

  int nt = K >> 5;
  STAGE(0, 0);
  int cur = 0;
  for (int t = 0; t < nt; ++t) {
    asm volatile("s_waitcnt vmcnt(0)" ::: "memory");
    __syncthreads();
    if (t + 1 < nt) STAGE((t + 1) << 5, cur ^ 1);
    shortx8 af[4], bf[4];
#pragma unroll
    for (int i = 0; i < 4; ++i) {
      af[i] = *(const shortx8*)((const char*)lds_a[cur] + (64 * wm + 16 * i + lr) * 64 + lg * 16);
      bf[i] = *(const shortx8*)((const char*)lds_b[cur] + (64 * wn + 16 * i + lr) * 64 + lg * 16);
    }
    __builtin_amdgcn_s_setprio(1);
#pragma unroll
    for (int mi = 0; mi < 4; ++mi)
#pragma unroll
      for (int ni = 0; ni < 4; ++ni)
        acc[mi][ni] = MFMA16(af[mi], bf[ni], acc[mi][ni]);
    __builtin_amdgcn_s_setprio(0);
    cur ^= 1;
  }
  // epilogue: Q,K -> qkv; V -> vt (transposed)
#pragma unroll
  for (int mi = 0; mi < 4; ++mi)
#pragma unroll
    for (int ni = 0; ni < 4; ++ni) {
      int col = n0 + 64 * wn + 16 * ni + lr;
      float bz = bias[col];
      int row0 = m0 + 64 * wm + 16 * mi + 4 * lg;
      if (col < 2048) {
#pragma unroll
        for (int r = 0; r < 4; ++r)
          qkv[(size_t)(row0 + r) * N + col] = f2bf(acc[mi][ni][r] + bz);
      } else {
        int dall = col - 2048;
        int h = dall >> 6, dd = dall & 63;
        int b_ = row0 >> 11, t_ = row0 & 2047;
        shortx4 o;
#pragma unroll
        for (int r = 0; r < 4; ++r) o[r] = (short)f2bf(acc[mi][ni][r] + bz);
        *(shortx4*)(vt + (size_t)((b_ * H_NUM + h) * DH + dd) * TSEQ + t_) = o;
      }
    }
}

// ---------------- 2-phase pipelined GEMM: C[M][N] = A[M][K] * Bt[N][K]^T + bias ----------------
template<int OUT_BF16>
__global__ __launch_bounds__(256) void k_gemm_bt(
    const u16* __restrict__ A, const u16* __restrict__ Bt,
    const float* __restrict__ bias, void* __restrict__ Cout,
    int M, int N, int K)
{
  __shared__ u16 lds_a[2][128 * 32];
  __shared__ u16 lds_b[2][128 * 32];
  int tid = threadIdx.x;
  int w = tid >> 6, l = tid & 63;
  int lg = l >> 4, lr = l & 15;
  int nwg = gridDim.x * gridDim.y;
  int lin = blockIdx.y * gridDim.x + blockIdx.x;
  int cpx = nwg >> 3;
  int swz = (lin & 7) * cpx + (lin >> 3);
  int m0 = (swz / gridDim.x) * 128, n0 = (swz % gridDim.x) * 128;
  int wm = w >> 1, wn = w & 1;
  f32x4 acc[4][4];
#pragma unroll
  for (int i = 0; i < 4; ++i)
#pragma unroll
    for (int j = 0; j < 4; ++j) acc[i][j] = (f32x4){0.f, 0.f, 0.f, 0.f};

  auto STAGE = [&](int k0, int buf) {
#pragma unroll
    for (int j = 0; j < 2; ++j) {
      int ci = w * 2 + j;
      gload_lds16(A  + (size_t)(m0 + ci * 16 + (l >> 2)) * K + k0 + (l & 3) * 8,
                  (char*)lds_a[buf] + ci * 1024);
      gload_lds16(Bt + (size_t)(n0 + ci * 16 + (l >> 2)) * K + k0 + (l & 3) * 8,
                  (char*)lds_b[buf] + ci * 1024);
    }
  };

  int nt = K >> 5;
  STAGE(0, 0);
  int cur = 0;
  for (int t = 0; t < nt; ++t) {
    asm volatile("s_waitcnt vmcnt(0)" ::: "memory");
    __syncthreads();
    if (t + 1 < nt) STAGE((t + 1) << 5, cur ^ 1);
    shortx8 af[4], bf[4];
#pragma unroll
    for (int i = 0; i < 4; ++i) {
      af[i] = *(const shortx8*)((const char*)lds_a[cur] + (64 * wm + 16 * i + lr) * 64 + lg * 16);
      bf[i] = *(const shortx8*)((const char*)lds_b[cur] + (64 * wn + 16 * i + lr) * 64 + lg * 16);
    }
    __builtin_amdgcn_s_setprio(1);
#pragma unroll
    for (int mi = 0; mi < 4; ++mi)
#pragma unroll
      for (int ni = 0; ni < 4; ++ni)
        acc[mi][ni] = MFMA16(af[mi], bf[ni], acc[mi][ni]);
    __builtin_amdgcn_s_setprio(0);
    cur ^= 1;
  }
  // epilogue
#pragma unroll
  for (int mi = 0; mi < 4; ++mi)
#pragma unroll
    for (int ni = 0; ni < 4; ++ni) {
      int col = n0 + 64 * wn + 16 * ni + lr;
      float bz = bias[col];
#pragma unroll
      for (int r = 0; r < 4; ++r) {
        int row = m0 + 64 * wm + 16 * mi + 4 * lg + r;
        float v = acc[mi][ni][r] + bz;
        if (OUT_BF16) ((u16*)Cout)[(size_t)row * N + col] = f2bf(v);
        else          ((float*)Cout)[(size_t)row * N + col] = v;
      }
    }
}

// ---------------- flash attention, causal, paired q-tiles, software-pipelined ----------------
// (byte-identical to the round-4 green kernel)
extern "C" __global__ __launch_bounds__(256) void k_attn(
    const u16* __restrict__ qkv, const u16* __restrict__ vt, u16* __restrict__ yb)
{
  __shared__ u16 lds_k[3][64 * 64];   // [buf][kv][d], XOR-swizzled chunks
  __shared__ u16 lds_v[3][64 * 64];   // [buf][d][kv], XOR-swizzled chunks
  __shared__ u16 lds_p[4 * 1024];     // per-wave [16 q][64 kv]
  // XCD-aware decode: xcd = d&7 fixed per (b,h) panel group
  int d = blockIdx.x;                 // 0..511
  int xcd = d & 7, j = d >> 3;        // j 0..63
  int hb = xcd + 8 * (j >> 4);        // 0..31, 4 panels per XCD
  int bx = j & 15;                    // q-pair 0..15
  int h = hb & 15, b = hb >> 4;
  int tid = threadIdx.x, w = tid >> 6, l = tid & 63;
  int lg = l >> 4, lr = l & 15;
  const float QSCALE = 0.18033688011112042f;  // 0.125 * log2(e)
  const u16* vbase = vt + (size_t)(b * H_NUM + h) * DH * TSEQ;
  u16* pw = lds_p + w * 1024;

  auto STAGE = [&](int kv0, int buf) {
#pragma unroll
    for (int jj = 0; jj < 2; ++jj) {
      int ci = w * 2 + jj;
      int row = ci * 8 + (l >> 3);
      int a = ((l & 7) ^ (row & 7)) * 8;
      gload_lds16(qkv + (size_t)(b * TSEQ + kv0 + row) * 3072 + CDIM + h * DH + a,
                  (char*)lds_k[buf] + ci * 1024);
      gload_lds16(vbase + (size_t)row * TSEQ + kv0 + a,
                  (char*)lds_v[buf] + ci * 1024);
    }
  };

  for (int qi = 0; qi < 2; ++qi) {
    int qb = qi ? (31 - bx) : bx;
    int q0 = qb * 64;

    // Q fragments, pre-scaled by 0.125*log2e
    int qrow = q0 + 16 * w + lr;
    const u16* qp = qkv + (size_t)(b * TSEQ + qrow) * 3072 + h * DH;
    shortx8 qf[2];
#pragma unroll
    for (int s_ = 0; s_ < 2; ++s_) {
      shortx8 v = *(const shortx8*)(qp + s_ * 32 + lg * 8);
#pragma unroll
      for (int i = 0; i < 8; ++i) v[i] = (short)f2bf(bf2f((u16)v[i]) * QSCALE);
      qf[s_] = v;
    }

    f32x4 yacc[4];
#pragma unroll
    for (int i = 0; i < 4; ++i) yacc[i] = (f32x4){0.f, 0.f, 0.f, 0.f};
    float m_run[4] = {-3.0e38f, -3.0e38f, -3.0e38f, -3.0e38f};
    float l_part[4] = {0.f, 0.f, 0.f, 0.f};
    f32x4 s[4];

    auto QKT = [&](int buf) {
#pragma unroll
      for (int idx = 0; idx < 4; ++idx) s[idx] = (f32x4){0.f, 0.f, 0.f, 0.f};
      int kswz = (lr & 7) << 4;
#pragma unroll
      for (int idx = 0; idx < 4; ++idx) {
        const char* kb_ = (const char*)lds_k[buf] + (idx * 16 + lr) * 128;
#pragma unroll
        for (int d0 = 0; d0 < 2; ++d0) {
          shortx8 kf = *(const shortx8*)(kb_ + ((d0 * 64 + lg * 16) ^ kswz));
          s[idx] = MFMA16(qf[d0], kf, s[idx]);
        }
      }
    };

    auto SOFTMAX = [&](int kv0) {
      if (kv0 == q0) {  // diagonal tile: apply causal mask
#pragma unroll
        for (int idx = 0; idx < 4; ++idx)
#pragma unroll
          for (int r = 0; r < 4; ++r) {
            int row_l = 16 * w + 4 * lg + r;
            if (idx * 16 + lr > row_l) s[idx][r] = -3.0e38f;
          }
      }
#pragma unroll
      for (int r = 0; r < 4; ++r) {
        float a0 = s[0][r], a1 = s[1][r], a2 = s[2][r], a3 = s[3][r];
        float pmax = fmaxf(fmaxf(a0, a1), fmaxf(a2, a3));
        float mr = m_run[r];
        u64 bal = __ballot(pmax > mr + 8.0f);
        if ((bal >> (lg * 16)) & 0xFFFFull) {
          float gm = pmax;
          gm = fmaxf(gm, __shfl_xor(gm, 1));
          gm = fmaxf(gm, __shfl_xor(gm, 2));
          gm = fmaxf(gm, __shfl_xor(gm, 4));
          gm = fmaxf(gm, __shfl_xor(gm, 8));
          float mn = fmaxf(mr, gm);
          float al = __builtin_amdgcn_exp2f(mr - mn);
          l_part[r] *= al;
#pragma unroll
          for (int dt = 0; dt < 4; ++dt) yacc[dt][r] *= al;
          m_run[r] = mn; mr = mn;
        }
        float p0 = __builtin_amdgcn_exp2f(a0 - mr);
        float p1 = __builtin_amdgcn_exp2f(a1 - mr);
        float p2 = __builtin_amdgcn_exp2f(a2 - mr);
        float p3 = __builtin_amdgcn_exp2f(a3 - mr);
        l_part[r] += (p0 + p1) + (p2 + p3);
        u32 pk01, pk23;
        asm("v_cvt_pk_bf16_f32 %0, %1, %2" : "=v"(pk01) : "v"(p0), "v"(p1));
        asm("v_cvt_pk_bf16_f32 %0, %1, %2" : "=v"(pk23) : "v"(p2), "v"(p3));
        int q = 4 * lg + r;
        int rb = q * 64, swq = (q & 7) << 3;
        pw[rb + ((lr)      ^ swq)] = (u16)pk01;
        pw[rb + ((16 + lr) ^ swq)] = (u16)(pk01 >> 16);
        pw[rb + ((32 + lr) ^ swq)] = (u16)pk23;
        pw[rb + ((48 + lr) ^ swq)] = (u16)(pk23 >> 16);
      }
    };

    auto PV = [&](int buf) {
      int pswz = (lr & 7) << 4;
#pragma unroll
      for (int c = 0; c < 2; ++c) {
        shortx8 pa = *(const shortx8*)((const char*)pw + lr * 128 + ((c * 64 + lg * 16) ^ pswz));
#pragma unroll
        for (int dt = 0; dt < 4; ++dt) {
          int vr = dt * 16 + lr;
          shortx8 vf = *(const shortx8*)((const char*)lds_v[buf] + vr * 128 +
                         ((c * 64 + lg * 16) ^ ((vr & 7) << 4)));
          yacc[dt] = MFMA16(pa, vf, yacc[dt]);
        }
      }
    };

    int nt = qb + 1;
    __syncthreads();            // all waves done reading LDS from previous qi
    STAGE(0, 0);
    asm volatile("s_waitcnt vmcnt(0)" ::: "memory");
    __syncthreads();            // buf0 complete & visible
    __builtin_amdgcn_s_setprio(1);
    QKT(0);
    __builtin_amdgcn_s_setprio(0);
    if (nt > 1) STAGE(64, 1);
    SOFTMAX(0);

    int vb = 0;                 // phase t: V from vb = t%3, K from kb = (t+1)%3
    for (int t = 0; t < nt; ++t) {
      int kb = vb + 1; if (kb == 3) kb = 0;
      int st = kb + 1; if (st == 3) st = 0;
      asm volatile("s_waitcnt vmcnt(0)" ::: "memory");
      __syncthreads();          // staged data (incl. buf kb) complete & visible
      __builtin_amdgcn_s_setprio(1);
      if (t + 1 < nt) QKT(kb);  // 8 MFMA, next tile's scores
      PV(vb);                   // 8 MFMA, this tile's PV (P written last phase)
      __builtin_amdgcn_s_setprio(0);
      if (t + 2 < nt) STAGE((t + 2) * 64, st);
      if (t + 1 < nt) SOFTMAX((t + 1) * 64);  // overlaps other wave's MFMA cluster
      vb = kb;
    }

    // epilogue: reduce deferred l, normalize, store
#pragma unroll
    for (int r = 0; r < 4; ++r) {
      float lsum = l_part[r];
      lsum += __shfl_xor(lsum, 1);
      lsum += __shfl_xor(lsum, 2);
      lsum += __shfl_xor(lsum, 4);
      lsum += __shfl_xor(lsum, 8);
      float inv = 1.0f / lsum;
      int row = q0 + 16 * w + 4 * lg + r;
      u16* yp = yb + (size_t)(b * TSEQ + row) * CDIM + h * DH;
#pragma unroll
      for (int dt = 0; dt < 4; ++dt)
        yp[dt * 16 + lr] = f2bf(yacc[dt][r] * inv);
    }
  }
}

extern "C" void kernel_launch(void* const* d_in, const int* in_sizes, int n_in,
                              void* d_out, int out_size, void* d_ws, size_t ws_size,
                              hipStream_t stream) {
  const float* x      = (const float*)d_in[0];
  const float* W_attn = (const float*)d_in[2];
  const float* b_attn = (const float*)d_in[3];
  const float* W_proj = (const float*)d_in[4];
  const float* b_proj = (const float*)d_in[5];

  char* ws = (char*)d_ws;
  u16* xb  = (u16*)ws;                         // 8 MB  [4096][1024]
  u16* wat = (u16*)(ws + (8ull  << 20));       // 6 MB  [3072][1024]
  u16* wpt = (u16*)(ws + (14ull << 20));       // 2 MB  [1024][1024]
  u16* qkv = (u16*)(ws + (16ull << 20));       // 24 MB [4096][3072] (V region unused)
  u16* vt  = (u16*)(ws + (40ull << 20));       // 8 MB  [32*64][2048]
  u16* yb  = (u16*)(ws + (48ull << 20));       // 8 MB  [4096][1024]

  k_prep<<<dim3(5120), dim3(1024), 0, stream>>>(x, xb, W_attn, wat, W_proj, wpt);
  k_gemm_qkv<<<dim3(24, 32), dim3(256), 0, stream>>>(xb, wat, b_attn, qkv, vt);
  k_attn<<<dim3(512), dim3(256), 0, stream>>>(qkv, vt, yb);
  k_gemm_bt<0><<<dim3(8, 32), dim3(256), 0, stream>>>(yb, wpt, b_proj, d_out, 4096, 1024, 1024);
}

// Round 7
// 121.366 us; speedup vs baseline: 1.1850x; 1.0152x over previous
//
#include <hip/hip_runtime.h>
#include <hip/hip_bf16.h>
#include <stdint.h>

#define H_NUM 16
#define DH 64
#define TSEQ 2048
#define CDIM 1024

typedef short shortx8 __attribute__((ext_vector_type(8)));
typedef short shortx4 __attribute__((ext_vector_type(4)));
typedef float f32x4 __attribute__((ext_vector_type(4)));
typedef unsigned short u16;
typedef unsigned int u32;
typedef unsigned long long u64;

#define MFMA16(a,b,c) __builtin_amdgcn_mfma_f32_16x16x32_bf16(a,b,c,0,0,0)

static __device__ __forceinline__ u16 f2bf(float f) {
  union { float f; u32 u; } v; v.f = f;
  u32 r = v.u + 0x7fffu + ((v.u >> 16) & 1u);
  return (u16)(r >> 16);
}
static __device__ __forceinline__ float bf2f(u16 b) {
  union { u32 u; float f; } v; v.u = ((u32)b) << 16;
  return v.f;
}

static __device__ __forceinline__ void gload_lds16(const void* g, void* l) {
  __builtin_amdgcn_global_load_lds(
    (const __attribute__((address_space(1))) void*)g,
    (__attribute__((address_space(3))) void*)l, 16, 0, 0);
}

// ---------------- fused prep: cast x -> bf16, transpose W_attn & W_proj -> bf16 ----------------
extern "C" __global__ __launch_bounds__(1024) void k_prep(
    const float* __restrict__ x, u16* __restrict__ xb,
    const float* __restrict__ Wa, u16* __restrict__ wat,
    const float* __restrict__ Wp, u16* __restrict__ wpt)
{
  __shared__ float t[32][33];
  int bid = blockIdx.x, tid = threadIdx.x;
  if (bid < 1024) {
    int i = bid * 1024 + tid;
    float4 v = ((const float4*)x)[i];
    union { u16 h[4]; uint2 u; } o;
    o.h[0] = f2bf(v.x); o.h[1] = f2bf(v.y); o.h[2] = f2bf(v.z); o.h[3] = f2bf(v.w);
    ((uint2*)xb)[i] = o.u;
    return;
  }
  const float* in; u16* out; int Ccols, bx, by;
  if (bid < 4096) { int tt = bid - 1024; in = Wa; out = wat; Ccols = 3072; bx = tt % 96; by = tt / 96; }
  else            { int tt = bid - 4096; in = Wp; out = wpt; Ccols = 1024; bx = tt & 31; by = tt >> 5; }
  int tx = tid & 31, ty = tid >> 5;
  int c0 = bx * 32, r0 = by * 32;
  t[ty][tx] = in[(size_t)(r0 + ty) * Ccols + c0 + tx];
  __syncthreads();
  out[(size_t)(c0 + ty) * 1024 + r0 + tx] = f2bf(t[tx][ty]);
}

// ---------------- QKV GEMM, 2-phase pipelined, fused V-transpose epilogue ----------------
extern "C" __global__ __launch_bounds__(256) void k_gemm_qkv(
    const u16* __restrict__ A, const u16* __restrict__ Bt,
    const float* __restrict__ bias, u16* __restrict__ qkv, u16* __restrict__ vt)
{
  const int K = 1024, N = 3072;
  __shared__ u16 lds_a[2][128 * 32];
  __shared__ u16 lds_b[2][128 * 32];
  int tid = threadIdx.x;
  int w = tid >> 6, l = tid & 63;
  int lg = l >> 4, lr = l & 15;
  int nwg = gridDim.x * gridDim.y;
  int lin = blockIdx.y * gridDim.x + blockIdx.x;
  int cpx = nwg >> 3;
  int swz = (lin & 7) * cpx + (lin >> 3);
  int m0 = (swz / gridDim.x) * 128, n0 = (swz % gridDim.x) * 128;
  int wm = w >> 1, wn = w & 1;
  f32x4 acc[4][4];
#pragma unroll
  for (int i = 0; i < 4; ++i)
#pragma unroll
    for (int j = 0; j < 4; ++j) acc[i][j] = (f32x4){0.f, 0.f, 0.f, 0.f};

  auto STAGE = [&](int k0, int buf) {
#pragma unroll
    for (int j = 0; j < 2; ++j) {
      int ci = w * 2 + j;
      gload_lds16(A  + (size_t)(m0 + ci * 16 + (l >> 2)) * K + k0 + (l & 3) * 8,
                  (char*)lds_a[buf] + ci * 1024);
      gload_lds16(Bt + (size_t)(n0 + ci * 16 + (l >> 2)) * K + k0 + (l & 3) * 8,
                  (char*)lds_b[buf] + ci * 1024);
    }
  };

  int nt = K >> 5;
  STAGE(0, 0);
  int cur = 0;
  for (int t = 0; t < nt; ++t) {
    asm volatile("s_waitcnt vmcnt(0)" ::: "memory");
    __syncthreads();
    if (t + 1 < nt) STAGE((t + 1) << 5, cur ^ 1);
    shortx8 af[4], bf[4];
#pragma unroll
    for (int i = 0; i < 4; ++i) {
      af[i] = *(const shortx8*)((const char*)lds_a[cur] + (64 * wm + 16 * i + lr) * 64 + lg * 16);
      bf[i] = *(const shortx8*)((const char*)lds_b[cur] + (64 * wn + 16 * i + lr) * 64 + lg * 16);
    }
    __builtin_amdgcn_s_setprio(1);
#pragma unroll
    for (int mi = 0; mi < 4; ++mi)
#pragma unroll
      for (int ni = 0; ni < 4; ++ni)
        acc[mi][ni] = MFMA16(af[mi], bf[ni], acc[mi][ni]);
    __builtin_amdgcn_s_setprio(0);
    cur ^= 1;
  }
  // epilogue: Q,K -> qkv; V -> vt (transposed)
#pragma unroll
  for (int mi = 0; mi < 4; ++mi)
#pragma unroll
    for (int ni = 0; ni < 4; ++ni) {
      int col = n0 + 64 * wn + 16 * ni + lr;
      float bz = bias[col];
      int row0 = m0 + 64 * wm + 16 * mi + 4 * lg;
      if (col < 2048) {
#pragma unroll
        for (int r = 0; r < 4; ++r)
          qkv[(size_t)(row0 + r) * N + col] = f2bf(acc[mi][ni][r] + bz);
      } else {
        int dall = col - 2048;
        int h = dall >> 6, dd = dall & 63;
        int b_ = row0 >> 11, t_ = row0 & 2047;
        shortx4 o;
#pragma unroll
        for (int r = 0; r < 4; ++r) o[r] = (short)f2bf(acc[mi][ni][r] + bz);
        *(shortx4*)(vt + (size_t)((b_ * H_NUM + h) * DH + dd) * TSEQ + t_) = o;
      }
    }
}

// ---------------- 2-phase pipelined GEMM: C[M][N] = A[M][K] * Bt[N][K]^T + bias ----------------
template<int OUT_BF16>
__global__ __launch_bounds__(256) void k_gemm_bt(
    const u16* __restrict__ A, const u16* __restrict__ Bt,
    const float* __restrict__ bias, void* __restrict__ Cout,
    int M, int N, int K)
{
  __shared__ u16 lds_a[2][128 * 32];
  __shared__ u16 lds_b[2][128 * 32];
  int tid = threadIdx.x;
  int w = tid >> 6, l = tid & 63;
  int lg = l >> 4, lr = l & 15;
  int nwg = gridDim.x * gridDim.y;
  int lin = blockIdx.y * gridDim.x + blockIdx.x;
  int cpx = nwg >> 3;
  int swz = (lin & 7) * cpx + (lin >> 3);
  int m0 = (swz / gridDim.x) * 128, n0 = (swz % gridDim.x) * 128;
  int wm = w >> 1, wn = w & 1;
  f32x4 acc[4][4];
#pragma unroll
  for (int i = 0; i < 4; ++i)
#pragma unroll
    for (int j = 0; j < 4; ++j) acc[i][j] = (f32x4){0.f, 0.f, 0.f, 0.f};

  auto STAGE = [&](int k0, int buf) {
#pragma unroll
    for (int j = 0; j < 2; ++j) {
      int ci = w * 2 + j;
      gload_lds16(A  + (size_t)(m0 + ci * 16 + (l >> 2)) * K + k0 + (l & 3) * 8,
                  (char*)lds_a[buf] + ci * 1024);
      gload_lds16(Bt + (size_t)(n0 + ci * 16 + (l >> 2)) * K + k0 + (l & 3) * 8,
                  (char*)lds_b[buf] + ci * 1024);
    }
  };

  int nt = K >> 5;
  STAGE(0, 0);
  int cur = 0;
  for (int t = 0; t < nt; ++t) {
    asm volatile("s_waitcnt vmcnt(0)" ::: "memory");
    __syncthreads();
    if (t + 1 < nt) STAGE((t + 1) << 5, cur ^ 1);
    shortx8 af[4], bf[4];
#pragma unroll
    for (int i = 0; i < 4; ++i) {
      af[i] = *(const shortx8*)((const char*)lds_a[cur] + (64 * wm + 16 * i + lr) * 64 + lg * 16);
      bf[i] = *(const shortx8*)((const char*)lds_b[cur] + (64 * wn + 16 * i + lr) * 64 + lg * 16);
    }
    __builtin_amdgcn_s_setprio(1);
#pragma unroll
    for (int mi = 0; mi < 4; ++mi)
#pragma unroll
      for (int ni = 0; ni < 4; ++ni)
        acc[mi][ni] = MFMA16(af[mi], bf[ni], acc[mi][ni]);
    __builtin_amdgcn_s_setprio(0);
    cur ^= 1;
  }
  // epilogue
#pragma unroll
  for (int mi = 0; mi < 4; ++mi)
#pragma unroll
    for (int ni = 0; ni < 4; ++ni) {
      int col = n0 + 64 * wn + 16 * ni + lr;
      float bz = bias[col];
#pragma unroll
      for (int r = 0; r < 4; ++r) {
        int row = m0 + 64 * wm + 16 * mi + 4 * lg + r;
        float v = acc[mi][ni][r] + bz;
        if (OUT_BF16) ((u16*)Cout)[(size_t)row * N + col] = f2bf(v);
        else          ((float*)Cout)[(size_t)row * N + col] = v;
      }
    }
}

// ---------------- flash attention, causal, paired q-tiles, KVBLK=128 ----------------
// grid (512), 256 threads, XCD-aware decode (unchanged). KV tile doubled to 128:
// 17 tiles/block (uniform: ceil((bx+1)/2)+ceil((32-bx)/2)=17), halving the per-tile
// fixed costs (vmcnt(0) drain + barrier + ballot/rescale) at IDENTICAL occupancy
// (80 KB LDS -> 2 blocks/CU, same as 57 KB). Same proven 2-buffer handshake as R0.
// Mask only on the last tile (only tile where kv can exceed q; proven by inequality).
// V rows are 256 B: chunk16 swizzle ^(row&15); P rows 256 B: same (q&7)<<3 u16 XOR.
extern "C" __global__ __launch_bounds__(256) void k_attn(
    const u16* __restrict__ qkv, const u16* __restrict__ vt, u16* __restrict__ yb)
{
  __shared__ u16 lds_k[2][128 * 64];   // [buf][kv][d], rows 128B, XOR-swizzled chunks
  __shared__ u16 lds_v[2][64 * 128];   // [buf][d][kv], rows 256B, XOR-swizzled chunks
  __shared__ u16 lds_p[4 * 2048];      // per-wave [16 q][128 kv]
  int d = blockIdx.x;                 // 0..511
  int xcd = d & 7, j = d >> 3;
  int hb = xcd + 8 * (j >> 4);
  int bx = j & 15;
  int h = hb & 15, b = hb >> 4;
  int tid = threadIdx.x, w = tid >> 6, l = tid & 63;
  int lg = l >> 4, lr = l & 15;
  const float QSCALE = 0.18033688011112042f;  // 0.125 * log2(e)
  const u16* vbase = vt + (size_t)(b * H_NUM + h) * DH * TSEQ;
  u16* pw = lds_p + w * 2048;

  // K: 16 instr (1KB = 8 rows x 128B); lane l -> row ci*8+(l>>3), chunk l&7,
  //    source chunk = (l&7)^(row&7) so swizzled reads are linear.
  // V: 16 instr (1KB = 4 rows x 256B); lane l -> row ci*4+(l>>4), chunk l&15,
  //    source chunk = (l&15)^(row&15).
  auto STAGE = [&](int kv0, int buf) {
#pragma unroll
    for (int jj = 0; jj < 4; ++jj) {
      int ci = w * 4 + jj;
      int krow = ci * 8 + (l >> 3);
      int ka = ((l & 7) ^ (krow & 7)) * 8;
      gload_lds16(qkv + (size_t)(b * TSEQ + kv0 + krow) * 3072 + CDIM + h * DH + ka,
                  (char*)lds_k[buf] + ci * 1024);
      int vrow = ci * 4 + (l >> 4);
      int va = ((l & 15) ^ (vrow & 15)) * 8;
      gload_lds16(vbase + (size_t)vrow * TSEQ + kv0 + va,
                  (char*)lds_v[buf] + ci * 1024);
    }
  };

  for (int qi = 0; qi < 2; ++qi) {
    int qb = qi ? (31 - bx) : bx;
    int q0 = qb * 64;

    // Q fragments, pre-scaled by 0.125*log2e
    int qrow = q0 + 16 * w + lr;
    const u16* qp = qkv + (size_t)(b * TSEQ + qrow) * 3072 + h * DH;
    shortx8 qf[2];
#pragma unroll
    for (int s_ = 0; s_ < 2; ++s_) {
      shortx8 v = *(const shortx8*)(qp + s_ * 32 + lg * 8);
#pragma unroll
      for (int i = 0; i < 8; ++i) v[i] = (short)f2bf(bf2f((u16)v[i]) * QSCALE);
      qf[s_] = v;
    }

    f32x4 yacc[4];
#pragma unroll
    for (int i = 0; i < 4; ++i) yacc[i] = (f32x4){0.f, 0.f, 0.f, 0.f};
    float m_run[4] = {-3.0e38f, -3.0e38f, -3.0e38f, -3.0e38f};
    float l_part[4] = {0.f, 0.f, 0.f, 0.f};

    int nt = (qb >> 1) + 1;     // tiles of 128 kv
    __syncthreads();            // previous readers of buf0 done
    STAGE(0, 0);
    int cur = 0;
    for (int t = 0; t < nt; ++t) {
      int kv0 = t * 128;
      asm volatile("s_waitcnt vmcnt(0)" ::: "memory");
      __syncthreads();          // buf[cur] complete & visible to all waves
      if (t + 1 < nt) STAGE(kv0 + 128, cur ^ 1);

      // ---- QK^T over 128 kv ----
      f32x4 s[8];
#pragma unroll
      for (int idx = 0; idx < 8; ++idx) s[idx] = (f32x4){0.f, 0.f, 0.f, 0.f};
      int kswz = (lr & 7) << 4;
      __builtin_amdgcn_s_setprio(1);
#pragma unroll
      for (int idx = 0; idx < 8; ++idx) {
        const char* kb_ = (const char*)lds_k[cur] + (idx * 16 + lr) * 128;
#pragma unroll
        for (int d0 = 0; d0 < 2; ++d0) {
          shortx8 kf = *(const shortx8*)(kb_ + ((d0 * 64 + lg * 16) ^ kswz));
          s[idx] = MFMA16(qf[d0], kf, s[idx]);
        }
      }
      __builtin_amdgcn_s_setprio(0);
      if (t == nt - 1) {        // only tile where kv can exceed q
        int base = q0 - kv0 + 16 * w + 4 * lg;
#pragma unroll
        for (int idx = 0; idx < 8; ++idx)
#pragma unroll
          for (int r = 0; r < 4; ++r)
            if (idx * 16 + lr > base + r) s[idx][r] = -3.0e38f;
      }

      // ---- online softmax (one pass per 128-kv tile) ----
#pragma unroll
      for (int r = 0; r < 4; ++r) {
        float a0 = s[0][r], a1 = s[1][r], a2 = s[2][r], a3 = s[3][r];
        float a4 = s[4][r], a5 = s[5][r], a6 = s[6][r], a7 = s[7][r];
        float pmax = fmaxf(fmaxf(fmaxf(a0, a1), fmaxf(a2, a3)),
                           fmaxf(fmaxf(a4, a5), fmaxf(a6, a7)));
        float mr = m_run[r];
        u64 bal = __ballot(pmax > mr + 8.0f);
        if ((bal >> (lg * 16)) & 0xFFFFull) {
          float gm = pmax;
          gm = fmaxf(gm, __shfl_xor(gm, 1));
          gm = fmaxf(gm, __shfl_xor(gm, 2));
          gm = fmaxf(gm, __shfl_xor(gm, 4));
          gm = fmaxf(gm, __shfl_xor(gm, 8));
          float mn = fmaxf(mr, gm);
          float al = __builtin_amdgcn_exp2f(mr - mn);
          l_part[r] *= al;
#pragma unroll
          for (int dt = 0; dt < 4; ++dt) yacc[dt][r] *= al;
          m_run[r] = mn; mr = mn;
        }
        float p0 = __builtin_amdgcn_exp2f(a0 - mr);
        float p1 = __builtin_amdgcn_exp2f(a1 - mr);
        float p2 = __builtin_amdgcn_exp2f(a2 - mr);
        float p3 = __builtin_amdgcn_exp2f(a3 - mr);
        float p4 = __builtin_amdgcn_exp2f(a4 - mr);
        float p5 = __builtin_amdgcn_exp2f(a5 - mr);
        float p6 = __builtin_amdgcn_exp2f(a6 - mr);
        float p7 = __builtin_amdgcn_exp2f(a7 - mr);
        l_part[r] += ((p0 + p1) + (p2 + p3)) + ((p4 + p5) + (p6 + p7));
        u32 pk01, pk23, pk45, pk67;
        asm("v_cvt_pk_bf16_f32 %0, %1, %2" : "=v"(pk01) : "v"(p0), "v"(p1));
        asm("v_cvt_pk_bf16_f32 %0, %1, %2" : "=v"(pk23) : "v"(p2), "v"(p3));
        asm("v_cvt_pk_bf16_f32 %0, %1, %2" : "=v"(pk45) : "v"(p4), "v"(p5));
        asm("v_cvt_pk_bf16_f32 %0, %1, %2" : "=v"(pk67) : "v"(p6), "v"(p7));
        int q = 4 * lg + r;
        int rb = q * 128, swq = (q & 7) << 3;
        pw[rb + ((lr)       ^ swq)] = (u16)pk01;
        pw[rb + ((16 + lr)  ^ swq)] = (u16)(pk01 >> 16);
        pw[rb + ((32 + lr)  ^ swq)] = (u16)pk23;
        pw[rb + ((48 + lr)  ^ swq)] = (u16)(pk23 >> 16);
        pw[rb + ((64 + lr)  ^ swq)] = (u16)pk45;
        pw[rb + ((80 + lr)  ^ swq)] = (u16)(pk45 >> 16);
        pw[rb + ((96 + lr)  ^ swq)] = (u16)pk67;
        pw[rb + ((112 + lr) ^ swq)] = (u16)(pk67 >> 16);
      }
      asm volatile("s_waitcnt lgkmcnt(0)" ::: "memory");
      __builtin_amdgcn_sched_barrier(0);

      // ---- PV over 128 kv ----
      int pswz = (lr & 7) << 4;
      __builtin_amdgcn_s_setprio(1);
#pragma unroll
      for (int c = 0; c < 4; ++c) {
        shortx8 pa = *(const shortx8*)((const char*)pw + lr * 256 + ((c * 64 + lg * 16) ^ pswz));
#pragma unroll
        for (int dt = 0; dt < 4; ++dt) {
          int vr = dt * 16 + lr;
          shortx8 vf = *(const shortx8*)((const char*)lds_v[cur] + vr * 256 +
                         (((c * 4 + lg) ^ (vr & 15)) << 4));
          yacc[dt] = MFMA16(pa, vf, yacc[dt]);
        }
      }
      __builtin_amdgcn_s_setprio(0);
      cur ^= 1;
    }

    // epilogue: reduce deferred l, normalize, store
#pragma unroll
    for (int r = 0; r < 4; ++r) {
      float lsum = l_part[r];
      lsum += __shfl_xor(lsum, 1);
      lsum += __shfl_xor(lsum, 2);
      lsum += __shfl_xor(lsum, 4);
      lsum += __shfl_xor(lsum, 8);
      float inv = 1.0f / lsum;
      int row = q0 + 16 * w + 4 * lg + r;
      u16* yp = yb + (size_t)(b * TSEQ + row) * CDIM + h * DH;
#pragma unroll
      for (int dt = 0; dt < 4; ++dt)
        yp[dt * 16 + lr] = f2bf(yacc[dt][r] * inv);
    }
  }
}

extern "C" void kernel_launch(void* const* d_in, const int* in_sizes, int n_in,
                              void* d_out, int out_size, void* d_ws, size_t ws_size,
                              hipStream_t stream) {
  const float* x      = (const float*)d_in[0];
  const float* W_attn = (const float*)d_in[2];
  const float* b_attn = (const float*)d_in[3];
  const float* W_proj = (const float*)d_in[4];
  const float* b_proj = (const float*)d_in[5];

  char* ws = (char*)d_ws;
  u16* xb  = (u16*)ws;                         // 8 MB  [4096][1024]
  u16* wat = (u16*)(ws + (8ull  << 20));       // 6 MB  [3072][1024]
  u16* wpt = (u16*)(ws + (14ull << 20));       // 2 MB  [1024][1024]
  u16* qkv = (u16*)(ws + (16ull << 20));       // 24 MB [4096][3072] (V region unused)
  u16* vt  = (u16*)(ws + (40ull << 20));       // 8 MB  [32*64][2048]
  u16* yb  = (u16*)(ws + (48ull << 20));       // 8 MB  [4096][1024]

  k_prep<<<dim3(5120), dim3(1024), 0, stream>>>(x, xb, W_attn, wat, W_proj, wpt);
  k_gemm_qkv<<<dim3(24, 32), dim3(256), 0, stream>>>(xb, wat, b_attn, qkv, vt);
  k_attn<<<dim3(512), dim3(256), 0, stream>>>(qkv, vt, yb);
  k_gemm_bt<0><<<dim3(8, 32), dim3(256), 0, stream>>>(yb, wpt, b_proj, d_out, 4096, 1024, 1024);
}